// Round 2
// baseline (248.498 us; speedup 1.0000x reference)
//
#include <hip/hip_runtime.h>
#include <hip/hip_bf16.h>

// MaskedAttentionHead: x[4,4096,1024] fp32; Wk,bk,Wq,bq,Wv,bv; out fp32 [4,4096,64]
// Round 1: resubmit round-0 pipeline (GPU acquisition timed out; no bench signal).
// 3-kernel pipeline, f16 MFMA (16x16x32), flash attention with online softmax.

typedef _Float16 f16;
typedef f16 half8 __attribute__((ext_vector_type(8)));
typedef float f32x4 __attribute__((ext_vector_type(4)));

#define T_SEQ 4096
#define C_DIM 1024
#define H_DIM 64
#define B_SZ 4

__device__ __forceinline__ f32x4 mfma16(half8 a, half8 b, f32x4 c) {
    return __builtin_amdgcn_mfma_f32_16x16x32_f16(a, b, c, 0, 0, 0);
}

// ---------------- Kernel 1: transpose weights to [3][64][1024] f16, fold 0.125 into Wq ----
__global__ __launch_bounds__(256) void prep_w(const float* __restrict__ Wq,
                                              const float* __restrict__ Wk,
                                              const float* __restrict__ Wv,
                                              f16* __restrict__ Wt) {
    int mat = blockIdx.x >> 4;            // 0=Q,1=K,2=V
    int k0 = (blockIdx.x & 15) << 6;
    const float* W = (mat == 0) ? Wq : (mat == 1 ? Wk : Wv);
    float s = (mat == 0) ? 0.125f : 1.0f; // fold softmax scale (exact power of 2) into Q
    __shared__ f16 t[64][72];
    int tid = threadIdx.x;
    int r = tid >> 2, c = (tid & 3) << 4;
#pragma unroll
    for (int q = 0; q < 4; ++q) {
        float4 v = *reinterpret_cast<const float4*>(&W[(size_t)(k0 + r) * 64 + c + q * 4]);
        t[r][c + q * 4 + 0] = (f16)(v.x * s);
        t[r][c + q * 4 + 1] = (f16)(v.y * s);
        t[r][c + q * 4 + 2] = (f16)(v.z * s);
        t[r][c + q * 4 + 3] = (f16)(v.w * s);
    }
    __syncthreads();
    int h = tid >> 2, kc = (tid & 3) << 4;
    half8 o0, o1;
#pragma unroll
    for (int i = 0; i < 8; ++i) { o0[i] = t[kc + i][h]; o1[i] = t[kc + 8 + i][h]; }
    *reinterpret_cast<half8*>(&Wt[(size_t)(mat * 64 + h) * 1024 + k0 + kc]) = o0;
    *reinterpret_cast<half8*>(&Wt[(size_t)(mat * 64 + h) * 1024 + k0 + kc + 8]) = o1;
}

// ---------------- Kernel 2: QKV projection: [16384,1024] @ [1024,192] -> f16 Q,K,V -------
__global__ __launch_bounds__(256) void proj(const float* __restrict__ x,
                                            const f16* __restrict__ Wt,
                                            const float* __restrict__ bk,
                                            const float* __restrict__ bq,
                                            const float* __restrict__ bv,
                                            f16* __restrict__ Qb, f16* __restrict__ Kb,
                                            f16* __restrict__ Vb) {
    __shared__ f16 xa[64][72];
    __shared__ f16 wt[192][72];
    __shared__ float bias_s[192];
    int tid = threadIdx.x;
    int m0 = blockIdx.x << 6;
    if (tid < 192) {
        int mat = tid >> 6, h = tid & 63;
        bias_s[tid] = (mat == 0) ? bq[h] * 0.125f : (mat == 1 ? bk[h] : bv[h]);
    }
    f32x4 zero = {0.f, 0.f, 0.f, 0.f};
    f32x4 acc[12];
#pragma unroll
    for (int i = 0; i < 12; ++i) acc[i] = zero;
    int w = tid >> 6, lane = tid & 63, g = lane >> 4, c16 = lane & 15;
    int xr = tid >> 2, xc = (tid & 3) << 4;
    int wn = tid >> 3, wk = (tid & 7) << 3;
    for (int kt = 0; kt < 16; ++kt) {
        int k0 = kt << 6;
        // stage x tile (64 rows x 64 cols) as f16
        half8 hv0, hv1;
#pragma unroll
        for (int q = 0; q < 4; ++q) {
            float4 v = *reinterpret_cast<const float4*>(
                &x[(size_t)(m0 + xr) * 1024 + k0 + xc + q * 4]);
            f16 e0 = (f16)v.x, e1 = (f16)v.y, e2 = (f16)v.z, e3 = (f16)v.w;
            if (q < 2) {
                hv0[q * 4 + 0] = e0; hv0[q * 4 + 1] = e1; hv0[q * 4 + 2] = e2; hv0[q * 4 + 3] = e3;
            } else {
                hv1[(q - 2) * 4 + 0] = e0; hv1[(q - 2) * 4 + 1] = e1;
                hv1[(q - 2) * 4 + 2] = e2; hv1[(q - 2) * 4 + 3] = e3;
            }
        }
        *reinterpret_cast<half8*>(&xa[xr][xc]) = hv0;
        *reinterpret_cast<half8*>(&xa[xr][xc + 8]) = hv1;
        // stage Wt tile (192 rows x 64 k) f16
#pragma unroll
        for (int p = 0; p < 6; ++p) {
            int n = p * 32 + wn;
            *reinterpret_cast<half8*>(&wt[n][wk]) =
                *reinterpret_cast<const half8*>(&Wt[(size_t)n * 1024 + k0 + wk]);
        }
        __syncthreads();
        half8 a0 = *reinterpret_cast<const half8*>(&xa[16 * w + c16][g * 8]);
        half8 a1 = *reinterpret_cast<const half8*>(&xa[16 * w + c16][32 + g * 8]);
#pragma unroll
        for (int nt = 0; nt < 12; ++nt) {
            half8 b0 = *reinterpret_cast<const half8*>(&wt[nt * 16 + c16][g * 8]);
            half8 b1 = *reinterpret_cast<const half8*>(&wt[nt * 16 + c16][32 + g * 8]);
            acc[nt] = mfma16(a0, b0, acc[nt]);
            acc[nt] = mfma16(a1, b1, acc[nt]);
        }
        __syncthreads();
    }
#pragma unroll
    for (int nt = 0; nt < 12; ++nt) {
        int mat = nt >> 2;
        int h = ((nt & 3) << 4) + c16;
        f16* outp = (mat == 0) ? Qb : (mat == 1 ? Kb : Vb);
#pragma unroll
        for (int j = 0; j < 4; ++j) {
            int row = m0 + 16 * w + g * 4 + j;
            outp[(size_t)row * 64 + h] = (f16)(acc[nt][j] + bias_s[mat * 64 + h]);
        }
    }
}

// ---------------- Kernel 3: causal flash attention, 64-row Q tile per block --------------
__global__ __launch_bounds__(256) void attn(const f16* __restrict__ Qb,
                                            const f16* __restrict__ Kb,
                                            const f16* __restrict__ Vb,
                                            float* __restrict__ out) {
    int qt = blockIdx.x, b = blockIdx.y;
    int q0 = qt << 6;
    size_t boff = (size_t)b * T_SEQ * 64;
    const f16* Q = Qb + boff;
    const f16* K = Kb + boff;
    const f16* V = Vb + boff;
    int tid = threadIdx.x;
    int w = tid >> 6, lane = tid & 63, g = lane >> 4, c16 = lane & 15;
    __shared__ f16 Kt[64][72];  // [key][h]
    __shared__ f16 Vt[64][72];  // [h][key] (transposed)
    __shared__ f16 Pl[4][16][72];

    // Q fragments (row = q0+16w+c16, k = h), Q pre-scaled by 0.125
    half8 qf0 = *reinterpret_cast<const half8*>(&Q[(size_t)(q0 + 16 * w + c16) * 64 + g * 8]);
    half8 qf1 = *reinterpret_cast<const half8*>(&Q[(size_t)(q0 + 16 * w + c16) * 64 + 32 + g * 8]);

    f32x4 zero = {0.f, 0.f, 0.f, 0.f};
    f32x4 oacc[4];
#pragma unroll
    for (int i = 0; i < 4; ++i) oacc[i] = zero;
    float m_run[4], l_run[4];
#pragma unroll
    for (int j = 0; j < 4; ++j) { m_run[j] = -__builtin_inff(); l_run[j] = 0.f; }

    int sr = tid >> 2, sc = (tid & 3) << 4;
    for (int kt = 0; kt <= qt; ++kt) {
        int k0 = kt << 6;
        // stage K tile [64][64]
        *reinterpret_cast<half8*>(&Kt[sr][sc]) =
            *reinterpret_cast<const half8*>(&K[(size_t)(k0 + sr) * 64 + sc]);
        *reinterpret_cast<half8*>(&Kt[sr][sc + 8]) =
            *reinterpret_cast<const half8*>(&K[(size_t)(k0 + sr) * 64 + sc + 8]);
        // stage V transposed
        half8 v0 = *reinterpret_cast<const half8*>(&V[(size_t)(k0 + sr) * 64 + sc]);
        half8 v1 = *reinterpret_cast<const half8*>(&V[(size_t)(k0 + sr) * 64 + sc + 8]);
#pragma unroll
        for (int i = 0; i < 8; ++i) { Vt[sc + i][sr] = v0[i]; Vt[sc + 8 + i][sr] = v1[i]; }
        __syncthreads();

        // S = Q @ K^T : [16 q-rows x 64 keys] per wave
        f32x4 s[4];
#pragma unroll
        for (int nt = 0; nt < 4; ++nt) s[nt] = zero;
#pragma unroll
        for (int nt = 0; nt < 4; ++nt) {
            half8 b0 = *reinterpret_cast<const half8*>(&Kt[nt * 16 + c16][g * 8]);
            half8 b1 = *reinterpret_cast<const half8*>(&Kt[nt * 16 + c16][32 + g * 8]);
            s[nt] = mfma16(qf0, b0, s[nt]);
            s[nt] = mfma16(qf1, b1, s[nt]);
        }
        // causal mask (only diagonal tile)
        if (kt == qt) {
#pragma unroll
            for (int nt = 0; nt < 4; ++nt)
#pragma unroll
                for (int j = 0; j < 4; ++j)
                    if (k0 + nt * 16 + c16 > q0 + 16 * w + g * 4 + j) s[nt][j] = -1e30f;
        }
        // online softmax: rows r = g*4+j, values spread over 16 lanes (lane&15) x 4 n-tiles
        float mx[4];
#pragma unroll
        for (int j = 0; j < 4; ++j)
            mx[j] = fmaxf(fmaxf(s[0][j], s[1][j]), fmaxf(s[2][j], s[3][j]));
#pragma unroll
        for (int off = 1; off < 16; off <<= 1)
#pragma unroll
            for (int j = 0; j < 4; ++j) mx[j] = fmaxf(mx[j], __shfl_xor(mx[j], off, 64));
        float al[4];
#pragma unroll
        for (int j = 0; j < 4; ++j) {
            float nm = fmaxf(m_run[j], mx[j]);
            al[j] = __expf(m_run[j] - nm);
            m_run[j] = nm;
        }
        float pm[4][4];
#pragma unroll
        for (int nt = 0; nt < 4; ++nt)
#pragma unroll
            for (int j = 0; j < 4; ++j) pm[nt][j] = __expf(s[nt][j] - m_run[j]);
        float rs[4];
#pragma unroll
        for (int j = 0; j < 4; ++j) rs[j] = pm[0][j] + pm[1][j] + pm[2][j] + pm[3][j];
#pragma unroll
        for (int off = 1; off < 16; off <<= 1)
#pragma unroll
            for (int j = 0; j < 4; ++j) rs[j] += __shfl_xor(rs[j], off, 64);
#pragma unroll
        for (int j = 0; j < 4; ++j) l_run[j] = l_run[j] * al[j] + rs[j];
#pragma unroll
        for (int ht = 0; ht < 4; ++ht)
#pragma unroll
            for (int j = 0; j < 4; ++j) oacc[ht][j] *= al[j];
        // P -> LDS (f16) for PV A-fragments
#pragma unroll
        for (int nt = 0; nt < 4; ++nt)
#pragma unroll
            for (int j = 0; j < 4; ++j) Pl[w][g * 4 + j][nt * 16 + c16] = (f16)pm[nt][j];
        half8 pa0 = *reinterpret_cast<const half8*>(&Pl[w][c16][g * 8]);
        half8 pa1 = *reinterpret_cast<const half8*>(&Pl[w][c16][32 + g * 8]);
#pragma unroll
        for (int ht = 0; ht < 4; ++ht) {
            half8 vb0 = *reinterpret_cast<const half8*>(&Vt[ht * 16 + c16][g * 8]);
            half8 vb1 = *reinterpret_cast<const half8*>(&Vt[ht * 16 + c16][32 + g * 8]);
            oacc[ht] = mfma16(pa0, vb0, oacc[ht]);
            oacc[ht] = mfma16(pa1, vb1, oacc[ht]);
        }
        __syncthreads();
    }
    // epilogue: out = oacc / l
#pragma unroll
    for (int j = 0; j < 4; ++j) {
        float rinv = 1.0f / l_run[j];
        int row = q0 + 16 * w + g * 4 + j;
#pragma unroll
        for (int ht = 0; ht < 4; ++ht)
            out[boff + (size_t)row * 64 + ht * 16 + c16] = oacc[ht][j] * rinv;
    }
}

extern "C" void kernel_launch(void* const* d_in, const int* in_sizes, int n_in,
                              void* d_out, int out_size, void* d_ws, size_t ws_size,
                              hipStream_t stream) {
    (void)in_sizes; (void)n_in; (void)out_size; (void)ws_size;
    const float* x  = (const float*)d_in[0];
    const float* Wk = (const float*)d_in[1];
    const float* bk = (const float*)d_in[2];
    const float* Wq = (const float*)d_in[3];
    const float* bq = (const float*)d_in[4];
    const float* Wv = (const float*)d_in[5];
    const float* bv = (const float*)d_in[6];
    float* out = (float*)d_out;
    char* ws = (char*)d_ws;
    f16* Wt = (f16*)ws;                                  // 192*1024*2  = 384 KiB
    f16* Qb = (f16*)(ws + 393216);                       // 16384*64*2 = 2 MiB
    f16* Kb = (f16*)(ws + 393216 + 2097152);
    f16* Vb = (f16*)(ws + 393216 + 2 * 2097152);

    prep_w<<<48, 256, 0, stream>>>(Wq, Wk, Wv, Wt);
    proj<<<256, 256, 0, stream>>>(x, Wt, bk, bq, bv, Qb, Kb, Vb);
    attn<<<dim3(64, 4), 256, 0, stream>>>(Qb, Kb, Vb, out);
}

// Round 3
// 242.495 us; speedup vs baseline: 1.0248x; 1.0248x over previous
//
#include <hip/hip_runtime.h>
#include <hip/hip_bf16.h>

// MaskedAttentionHead: x[4,4096,1024] fp32 -> out fp32 [4,4096,64]
// Round 2: (a) proj as 1024 single-wave register GEMMs (no LDS/barriers),
// (b) flash attention split-KV (4 chunks) + double-buffered K/V prefetch,
// (c) V stored transposed for coalesced attn staging, (d) combine pass.

typedef _Float16 f16;
typedef f16 half8 __attribute__((ext_vector_type(8)));
typedef float f32x4 __attribute__((ext_vector_type(4)));

#define T_SEQ 4096

__device__ __forceinline__ f32x4 mfma16(half8 a, half8 b, f32x4 c) {
    return __builtin_amdgcn_mfma_f32_16x16x32_f16(a, b, c, 0, 0, 0);
}

// ---- Kernel 1: W^T -> [3][64][1024] f16, fold softmax scale 0.125 into Wq ----
__global__ __launch_bounds__(256) void prep_w(const float* __restrict__ Wq,
                                              const float* __restrict__ Wk,
                                              const float* __restrict__ Wv,
                                              f16* __restrict__ Wt) {
    int mat = blockIdx.x >> 4;
    int k0 = (blockIdx.x & 15) << 6;
    const float* W = (mat == 0) ? Wq : (mat == 1 ? Wk : Wv);
    float s = (mat == 0) ? 0.125f : 1.0f;
    __shared__ f16 t[64][72];
    int tid = threadIdx.x;
    int r = tid >> 2, c = (tid & 3) << 4;
#pragma unroll
    for (int q = 0; q < 4; ++q) {
        float4 v = *reinterpret_cast<const float4*>(&W[(size_t)(k0 + r) * 64 + c + q * 4]);
        t[r][c + q * 4 + 0] = (f16)(v.x * s);
        t[r][c + q * 4 + 1] = (f16)(v.y * s);
        t[r][c + q * 4 + 2] = (f16)(v.z * s);
        t[r][c + q * 4 + 3] = (f16)(v.w * s);
    }
    __syncthreads();
    int h = tid >> 2, kc = (tid & 3) << 4;
    half8 o0, o1;
#pragma unroll
    for (int i = 0; i < 8; ++i) { o0[i] = t[kc + i][h]; o1[i] = t[kc + 8 + i][h]; }
    *reinterpret_cast<half8*>(&Wt[(size_t)(mat * 64 + h) * 1024 + k0 + kc]) = o0;
    *reinterpret_cast<half8*>(&Wt[(size_t)(mat * 64 + h) * 1024 + k0 + kc + 8]) = o1;
}

// ---- Kernel 2: QKV projection, one wave per 16-row tile, register-only GEMM ----
// Q,K row-major [16384][64]; V transposed [4][64][4096].
__global__ __launch_bounds__(64) void proj(const float* __restrict__ x,
                                           const f16* __restrict__ Wt,
                                           const float* __restrict__ bk,
                                           const float* __restrict__ bq,
                                           const float* __restrict__ bv,
                                           f16* __restrict__ Qb, f16* __restrict__ Kb,
                                           f16* __restrict__ Vbt) {
    int m0 = blockIdx.x << 4;
    int lane = threadIdx.x;
    int g = lane >> 4, c16 = lane & 15;
    f32x4 zero = {0.f, 0.f, 0.f, 0.f};
    f32x4 acc[12];
#pragma unroll
    for (int i = 0; i < 12; ++i) acc[i] = zero;
    const float* xrow = &x[(size_t)(m0 + c16) * 1024 + g * 8];
#pragma unroll 4
    for (int ks = 0; ks < 32; ++ks) {
        int k0 = ks << 5;
        float4 xa0 = *reinterpret_cast<const float4*>(xrow + k0);
        float4 xa1 = *reinterpret_cast<const float4*>(xrow + k0 + 4);
        half8 a;
        a[0] = (f16)xa0.x; a[1] = (f16)xa0.y; a[2] = (f16)xa0.z; a[3] = (f16)xa0.w;
        a[4] = (f16)xa1.x; a[5] = (f16)xa1.y; a[6] = (f16)xa1.z; a[7] = (f16)xa1.w;
#pragma unroll
        for (int nt = 0; nt < 12; ++nt) {
            half8 bf = *reinterpret_cast<const half8*>(
                &Wt[(size_t)(nt * 16 + c16) * 1024 + k0 + g * 8]);
            acc[nt] = mfma16(a, bf, acc[nt]);
        }
    }
    int b = m0 >> 12;
#pragma unroll
    for (int nt = 0; nt < 12; ++nt) {
        int mat = nt >> 2;
        int h = ((nt & 3) << 4) + c16;
        float bias = (mat == 0) ? bq[h] * 0.125f : (mat == 1 ? bk[h] : bv[h]);
#pragma unroll
        for (int j = 0; j < 4; ++j) {
            int row = m0 + g * 4 + j;
            f16 val = (f16)(acc[nt][j] + bias);
            if (mat == 0) Qb[(size_t)row * 64 + h] = val;
            else if (mat == 1) Kb[(size_t)row * 64 + h] = val;
            else Vbt[((size_t)(b * 64 + h)) * 4096 + (row & 4095)] = val;
        }
    }
}

// ---- Kernel 3: flash attention over one KV chunk (<=16 tiles of 64 keys) ----
__global__ __launch_bounds__(256) void attn(const f16* __restrict__ Qb,
                                            const f16* __restrict__ Kb,
                                            const f16* __restrict__ Vbt,
                                            f16* __restrict__ Opart,
                                            float* __restrict__ Ml) {
    int qt = blockIdx.x, b = blockIdx.y, ck = blockIdx.z;
    int t0 = ck << 4;
    if (t0 > qt) return;
    int nT = min(t0 + 16, qt + 1);
    int nIter = nT - t0;
    int q0 = qt << 6;
    const f16* Q = Qb + (size_t)b * T_SEQ * 64;
    const f16* K = Kb + (size_t)b * T_SEQ * 64;
    const f16* Vg = Vbt + (size_t)b * 64 * T_SEQ;
    int tid = threadIdx.x;
    int w = tid >> 6, lane = tid & 63, g = lane >> 4, c16 = lane & 15;
    __shared__ f16 Kt[2][64][72];   // [buf][key][h]
    __shared__ f16 Vt[2][64][72];   // [buf][h][key]
    __shared__ f16 Pl[4][16][72];

    half8 qf0 = *reinterpret_cast<const half8*>(&Q[(size_t)(q0 + 16 * w + c16) * 64 + g * 8]);
    half8 qf1 = *reinterpret_cast<const half8*>(&Q[(size_t)(q0 + 16 * w + c16) * 64 + 32 + g * 8]);

    f32x4 zero = {0.f, 0.f, 0.f, 0.f};
    f32x4 oacc[4];
#pragma unroll
    for (int i = 0; i < 4; ++i) oacc[i] = zero;
    float m_run[4], l_run[4];
#pragma unroll
    for (int j = 0; j < 4; ++j) { m_run[j] = -__builtin_inff(); l_run[j] = 0.f; }

    int sr = tid >> 2, sc = (tid & 3) << 4;
    // prologue: stage tile t0 into buf 0
    int k0 = t0 << 6;
    half8 kr0 = *reinterpret_cast<const half8*>(&K[(size_t)(k0 + sr) * 64 + sc]);
    half8 kr1 = *reinterpret_cast<const half8*>(&K[(size_t)(k0 + sr) * 64 + sc + 8]);
    half8 vr0 = *reinterpret_cast<const half8*>(&Vg[(size_t)sr * T_SEQ + k0 + sc]);
    half8 vr1 = *reinterpret_cast<const half8*>(&Vg[(size_t)sr * T_SEQ + k0 + sc + 8]);
    *reinterpret_cast<half8*>(&Kt[0][sr][sc]) = kr0;
    *reinterpret_cast<half8*>(&Kt[0][sr][sc + 8]) = kr1;
    *reinterpret_cast<half8*>(&Vt[0][sr][sc]) = vr0;
    *reinterpret_cast<half8*>(&Vt[0][sr][sc + 8]) = vr1;
    __syncthreads();
    int cur = 0;

    for (int it = 0; it < nIter; ++it) {
        int gt = t0 + it;
        if (it + 1 < nIter) {  // issue next tile's loads early (hide under compute)
            int kn = (gt + 1) << 6;
            kr0 = *reinterpret_cast<const half8*>(&K[(size_t)(kn + sr) * 64 + sc]);
            kr1 = *reinterpret_cast<const half8*>(&K[(size_t)(kn + sr) * 64 + sc + 8]);
            vr0 = *reinterpret_cast<const half8*>(&Vg[(size_t)sr * T_SEQ + kn + sc]);
            vr1 = *reinterpret_cast<const half8*>(&Vg[(size_t)sr * T_SEQ + kn + sc + 8]);
        }
        // S = Q @ K^T
        f32x4 s[4];
#pragma unroll
        for (int nt = 0; nt < 4; ++nt) s[nt] = zero;
#pragma unroll
        for (int nt = 0; nt < 4; ++nt) {
            half8 b0 = *reinterpret_cast<const half8*>(&Kt[cur][nt * 16 + c16][g * 8]);
            half8 b1 = *reinterpret_cast<const half8*>(&Kt[cur][nt * 16 + c16][32 + g * 8]);
            s[nt] = mfma16(qf0, b0, s[nt]);
            s[nt] = mfma16(qf1, b1, s[nt]);
        }
        if (gt == qt) {
            int kb = gt << 6;
#pragma unroll
            for (int nt = 0; nt < 4; ++nt)
#pragma unroll
                for (int j = 0; j < 4; ++j)
                    if (kb + nt * 16 + c16 > q0 + 16 * w + g * 4 + j) s[nt][j] = -1e30f;
        }
        float mx[4];
#pragma unroll
        for (int j = 0; j < 4; ++j)
            mx[j] = fmaxf(fmaxf(s[0][j], s[1][j]), fmaxf(s[2][j], s[3][j]));
#pragma unroll
        for (int off = 1; off < 16; off <<= 1)
#pragma unroll
            for (int j = 0; j < 4; ++j) mx[j] = fmaxf(mx[j], __shfl_xor(mx[j], off, 64));
        float al[4];
#pragma unroll
        for (int j = 0; j < 4; ++j) {
            float nm = fmaxf(m_run[j], mx[j]);
            al[j] = __expf(m_run[j] - nm);
            m_run[j] = nm;
        }
        float pm[4][4];
#pragma unroll
        for (int nt = 0; nt < 4; ++nt)
#pragma unroll
            for (int j = 0; j < 4; ++j) pm[nt][j] = __expf(s[nt][j] - m_run[j]);
        float rs[4];
#pragma unroll
        for (int j = 0; j < 4; ++j) rs[j] = pm[0][j] + pm[1][j] + pm[2][j] + pm[3][j];
#pragma unroll
        for (int off = 1; off < 16; off <<= 1)
#pragma unroll
            for (int j = 0; j < 4; ++j) rs[j] += __shfl_xor(rs[j], off, 64);
#pragma unroll
        for (int j = 0; j < 4; ++j) l_run[j] = l_run[j] * al[j] + rs[j];
#pragma unroll
        for (int ht = 0; ht < 4; ++ht)
#pragma unroll
            for (int j = 0; j < 4; ++j) oacc[ht][j] *= al[j];
#pragma unroll
        for (int nt = 0; nt < 4; ++nt)
#pragma unroll
            for (int j = 0; j < 4; ++j) Pl[w][g * 4 + j][nt * 16 + c16] = (f16)pm[nt][j];
        half8 pa0 = *reinterpret_cast<const half8*>(&Pl[w][c16][g * 8]);
        half8 pa1 = *reinterpret_cast<const half8*>(&Pl[w][c16][32 + g * 8]);
#pragma unroll
        for (int ht = 0; ht < 4; ++ht) {
            half8 vb0 = *reinterpret_cast<const half8*>(&Vt[cur][ht * 16 + c16][g * 8]);
            half8 vb1 = *reinterpret_cast<const half8*>(&Vt[cur][ht * 16 + c16][32 + g * 8]);
            oacc[ht] = mfma16(pa0, vb0, oacc[ht]);
            oacc[ht] = mfma16(pa1, vb1, oacc[ht]);
        }
        if (it + 1 < nIter) {
            *reinterpret_cast<half8*>(&Kt[cur ^ 1][sr][sc]) = kr0;
            *reinterpret_cast<half8*>(&Kt[cur ^ 1][sr][sc + 8]) = kr1;
            *reinterpret_cast<half8*>(&Vt[cur ^ 1][sr][sc]) = vr0;
            *reinterpret_cast<half8*>(&Vt[cur ^ 1][sr][sc + 8]) = vr1;
        }
        __syncthreads();
        cur ^= 1;
    }
    // write partial O (f16) + m/l
    int slot = (((b << 6) + qt) << 2) + ck;
    f16* Op = Opart + (size_t)slot * 4096;
    float* mlp = Ml + (size_t)slot * 128;
#pragma unroll
    for (int j = 0; j < 4; ++j) {
        int r = 16 * w + g * 4 + j;
#pragma unroll
        for (int ht = 0; ht < 4; ++ht)
            Op[r * 64 + ht * 16 + c16] = (f16)oacc[ht][j];
        if (c16 == 0) { mlp[r] = m_run[j]; mlp[64 + r] = l_run[j]; }
    }
}

// ---- Kernel 4: combine split-KV partials ----
__global__ __launch_bounds__(256) void combine(const f16* __restrict__ Opart,
                                               const float* __restrict__ Ml,
                                               float* __restrict__ out) {
    int qt = blockIdx.x, b = blockIdx.y;
    int nck = (qt >> 4) + 1;
    int tid = threadIdx.x;
    int row = tid >> 2, c0 = (tid & 3) << 4;
    int bslot = ((b << 6) + qt) << 2;
    float mv[4], lv[4];
    float M = -1e30f;
#pragma unroll
    for (int i = 0; i < 4; ++i)
        if (i < nck) {
            mv[i] = Ml[(size_t)(bslot + i) * 128 + row];
            lv[i] = Ml[(size_t)(bslot + i) * 128 + 64 + row];
            M = fmaxf(M, mv[i]);
        }
    float L = 0.f, sc[4];
#pragma unroll
    for (int i = 0; i < 4; ++i)
        if (i < nck) { sc[i] = __expf(mv[i] - M); L += lv[i] * sc[i]; }
    float inv = 1.0f / L;
    float o[16];
#pragma unroll
    for (int j = 0; j < 16; ++j) o[j] = 0.f;
#pragma unroll
    for (int i = 0; i < 4; ++i)
        if (i < nck) {
            const f16* Op = Opart + (size_t)(bslot + i) * 4096 + row * 64 + c0;
            half8 h0 = *reinterpret_cast<const half8*>(Op);
            half8 h1 = *reinterpret_cast<const half8*>(Op + 8);
#pragma unroll
            for (int j = 0; j < 8; ++j) {
                o[j] += sc[i] * (float)h0[j];
                o[8 + j] += sc[i] * (float)h1[j];
            }
        }
    float* op = &out[((size_t)b * T_SEQ + (qt << 6) + row) * 64 + c0];
#pragma unroll
    for (int j = 0; j < 16; ++j) op[j] = o[j] * inv;
}

extern "C" void kernel_launch(void* const* d_in, const int* in_sizes, int n_in,
                              void* d_out, int out_size, void* d_ws, size_t ws_size,
                              hipStream_t stream) {
    (void)in_sizes; (void)n_in; (void)out_size; (void)ws_size;
    const float* x  = (const float*)d_in[0];
    const float* Wk = (const float*)d_in[1];
    const float* bk = (const float*)d_in[2];
    const float* Wq = (const float*)d_in[3];
    const float* bq = (const float*)d_in[4];
    const float* Wv = (const float*)d_in[5];
    const float* bv = (const float*)d_in[6];
    float* out = (float*)d_out;
    char* ws = (char*)d_ws;
    f16* Wt   = (f16*)(ws);                        // 393216 B
    f16* Qb   = (f16*)(ws + 393216);               // 2 MiB
    f16* Kb   = (f16*)(ws + 393216 + 2097152);     // 2 MiB
    f16* Vbt  = (f16*)(ws + 393216 + 2 * 2097152); // 2 MiB (transposed)
    f16* Opart= (f16*)(ws + 393216 + 3 * 2097152);          // 8 MiB
    float* Ml = (float*)(ws + 393216 + 3 * 2097152 + 8388608); // 512 KiB

    prep_w<<<48, 256, 0, stream>>>(Wq, Wk, Wv, Wt);
    proj<<<1024, 64, 0, stream>>>(x, Wt, bk, bq, bv, Qb, Kb, Vbt);
    attn<<<dim3(64, 4, 4), 256, 0, stream>>>(Qb, Kb, Vbt, Opart, Ml);
    combine<<<dim3(64, 4), 256, 0, stream>>>(Opart, Ml, out);
}

// Round 4
// 196.439 us; speedup vs baseline: 1.2650x; 1.2345x over previous
//
#include <hip/hip_runtime.h>
#include <hip/hip_bf16.h>

// MaskedAttentionHead: x[4,4096,1024] fp32 -> out fp32 [4,4096,64]
// Round 3: proj rewritten — 4 waves/block (n-split, no barriers), W pre-packed in
// MFMA fragment order (contiguous 1KB/wave B-fragment loads). attn/combine unchanged.

typedef _Float16 f16;
typedef f16 half8 __attribute__((ext_vector_type(8)));
typedef float f32x4 __attribute__((ext_vector_type(4)));

#define T_SEQ 4096

__device__ __forceinline__ f32x4 mfma16(half8 a, half8 b, f32x4 c) {
    return __builtin_amdgcn_mfma_f32_16x16x32_f16(a, b, c, 0, 0, 0);
}

// ---- Kernel 1: pack W into fragment order Wfrag[nt][ks][lane][8] f16 ----
// element: h = (nt&3)*16 + (lane&15) within mat nt>>2 ; k = ks*32 + (lane>>4)*8 + j
__global__ __launch_bounds__(256) void prep_w(const float* __restrict__ Wq,
                                              const float* __restrict__ Wk,
                                              const float* __restrict__ Wv,
                                              f16* __restrict__ Wfrag) {
    int nt = blockIdx.x;               // 0..11
    int mat = nt >> 2;
    const float* W = (mat == 0) ? Wq : (mat == 1 ? Wk : Wv);
    float s = (mat == 0) ? 0.125f : 1.0f;   // fold softmax scale into Wq
    int tid = threadIdx.x;
    int lane = tid & 63, g = lane >> 4, c16 = lane & 15;
    int ksb = (tid >> 6) * 8;
    int h = ((nt & 3) << 4) + c16;
#pragma unroll
    for (int q = 0; q < 8; ++q) {
        int ks = ksb + q;
        half8 o;
#pragma unroll
        for (int j = 0; j < 8; ++j) {
            int k = ks * 32 + g * 8 + j;
            o[j] = (f16)(W[(size_t)k * 64 + h] * s);
        }
        *reinterpret_cast<half8*>(&Wfrag[((size_t)(nt * 32 + ks) * 64 + lane) * 8]) = o;
    }
}

// ---- Kernel 2: QKV projection. 1024 blocks x 256 thr; wave w owns n-tiles w*3..w*3+2.
// Q,K row-major [16384][64]; V transposed [4][64][4096].
__global__ __launch_bounds__(256) void proj(const float* __restrict__ x,
                                            const f16* __restrict__ Wfrag,
                                            const float* __restrict__ bk,
                                            const float* __restrict__ bq,
                                            const float* __restrict__ bv,
                                            f16* __restrict__ Qb, f16* __restrict__ Kb,
                                            f16* __restrict__ Vbt) {
    int m0 = blockIdx.x << 4;
    int tid = threadIdx.x;
    int w = tid >> 6, lane = tid & 63, g = lane >> 4, c16 = lane & 15;
    f32x4 zero = {0.f, 0.f, 0.f, 0.f};
    f32x4 acc[3];
#pragma unroll
    for (int i = 0; i < 3; ++i) acc[i] = zero;
    const float* xrow = &x[(size_t)(m0 + c16) * 1024 + g * 8];
    const f16* wbase = &Wfrag[(size_t)(w * 3) * 32 * 64 * 8 + (size_t)lane * 8];
#pragma unroll 8
    for (int ks = 0; ks < 32; ++ks) {
        float4 xa0 = *reinterpret_cast<const float4*>(xrow + ks * 32);
        float4 xa1 = *reinterpret_cast<const float4*>(xrow + ks * 32 + 4);
        half8 a;
        a[0] = (f16)xa0.x; a[1] = (f16)xa0.y; a[2] = (f16)xa0.z; a[3] = (f16)xa0.w;
        a[4] = (f16)xa1.x; a[5] = (f16)xa1.y; a[6] = (f16)xa1.z; a[7] = (f16)xa1.w;
#pragma unroll
        for (int i = 0; i < 3; ++i) {
            half8 bf = *reinterpret_cast<const half8*>(
                wbase + ((size_t)i * 32 + ks) * 64 * 8);
            acc[i] = mfma16(a, bf, acc[i]);
        }
    }
    int b = m0 >> 12;
#pragma unroll
    for (int i = 0; i < 3; ++i) {
        int nt = w * 3 + i;
        int mat = nt >> 2;
        int h = ((nt & 3) << 4) + c16;
        float bias = (mat == 0) ? bq[h] * 0.125f : (mat == 1 ? bk[h] : bv[h]);
#pragma unroll
        for (int j = 0; j < 4; ++j) {
            int row = m0 + g * 4 + j;
            f16 val = (f16)(acc[i][j] + bias);
            if (mat == 0) Qb[(size_t)row * 64 + h] = val;
            else if (mat == 1) Kb[(size_t)row * 64 + h] = val;
            else Vbt[((size_t)(b * 64 + h)) * 4096 + (row & 4095)] = val;
        }
    }
}

// ---- Kernel 3: flash attention over one KV chunk (<=16 tiles of 64 keys) ----
__global__ __launch_bounds__(256) void attn(const f16* __restrict__ Qb,
                                            const f16* __restrict__ Kb,
                                            const f16* __restrict__ Vbt,
                                            f16* __restrict__ Opart,
                                            float* __restrict__ Ml) {
    int qt = blockIdx.x, b = blockIdx.y, ck = blockIdx.z;
    int t0 = ck << 4;
    if (t0 > qt) return;
    int nT = min(t0 + 16, qt + 1);
    int nIter = nT - t0;
    int q0 = qt << 6;
    const f16* Q = Qb + (size_t)b * T_SEQ * 64;
    const f16* K = Kb + (size_t)b * T_SEQ * 64;
    const f16* Vg = Vbt + (size_t)b * 64 * T_SEQ;
    int tid = threadIdx.x;
    int w = tid >> 6, lane = tid & 63, g = lane >> 4, c16 = lane & 15;
    __shared__ f16 Kt[2][64][72];   // [buf][key][h]
    __shared__ f16 Vt[2][64][72];   // [buf][h][key]
    __shared__ f16 Pl[4][16][72];

    half8 qf0 = *reinterpret_cast<const half8*>(&Q[(size_t)(q0 + 16 * w + c16) * 64 + g * 8]);
    half8 qf1 = *reinterpret_cast<const half8*>(&Q[(size_t)(q0 + 16 * w + c16) * 64 + 32 + g * 8]);

    f32x4 zero = {0.f, 0.f, 0.f, 0.f};
    f32x4 oacc[4];
#pragma unroll
    for (int i = 0; i < 4; ++i) oacc[i] = zero;
    float m_run[4], l_run[4];
#pragma unroll
    for (int j = 0; j < 4; ++j) { m_run[j] = -__builtin_inff(); l_run[j] = 0.f; }

    int sr = tid >> 2, sc = (tid & 3) << 4;
    int k0 = t0 << 6;
    half8 kr0 = *reinterpret_cast<const half8*>(&K[(size_t)(k0 + sr) * 64 + sc]);
    half8 kr1 = *reinterpret_cast<const half8*>(&K[(size_t)(k0 + sr) * 64 + sc + 8]);
    half8 vr0 = *reinterpret_cast<const half8*>(&Vg[(size_t)sr * T_SEQ + k0 + sc]);
    half8 vr1 = *reinterpret_cast<const half8*>(&Vg[(size_t)sr * T_SEQ + k0 + sc + 8]);
    *reinterpret_cast<half8*>(&Kt[0][sr][sc]) = kr0;
    *reinterpret_cast<half8*>(&Kt[0][sr][sc + 8]) = kr1;
    *reinterpret_cast<half8*>(&Vt[0][sr][sc]) = vr0;
    *reinterpret_cast<half8*>(&Vt[0][sr][sc + 8]) = vr1;
    __syncthreads();
    int cur = 0;

    for (int it = 0; it < nIter; ++it) {
        int gt = t0 + it;
        if (it + 1 < nIter) {
            int kn = (gt + 1) << 6;
            kr0 = *reinterpret_cast<const half8*>(&K[(size_t)(kn + sr) * 64 + sc]);
            kr1 = *reinterpret_cast<const half8*>(&K[(size_t)(kn + sr) * 64 + sc + 8]);
            vr0 = *reinterpret_cast<const half8*>(&Vg[(size_t)sr * T_SEQ + kn + sc]);
            vr1 = *reinterpret_cast<const half8*>(&Vg[(size_t)sr * T_SEQ + kn + sc + 8]);
        }
        f32x4 s[4];
#pragma unroll
        for (int nt = 0; nt < 4; ++nt) s[nt] = zero;
#pragma unroll
        for (int nt = 0; nt < 4; ++nt) {
            half8 b0 = *reinterpret_cast<const half8*>(&Kt[cur][nt * 16 + c16][g * 8]);
            half8 b1 = *reinterpret_cast<const half8*>(&Kt[cur][nt * 16 + c16][32 + g * 8]);
            s[nt] = mfma16(qf0, b0, s[nt]);
            s[nt] = mfma16(qf1, b1, s[nt]);
        }
        if (gt == qt) {
            int kb = gt << 6;
#pragma unroll
            for (int nt = 0; nt < 4; ++nt)
#pragma unroll
                for (int j = 0; j < 4; ++j)
                    if (kb + nt * 16 + c16 > q0 + 16 * w + g * 4 + j) s[nt][j] = -1e30f;
        }
        float mx[4];
#pragma unroll
        for (int j = 0; j < 4; ++j)
            mx[j] = fmaxf(fmaxf(s[0][j], s[1][j]), fmaxf(s[2][j], s[3][j]));
#pragma unroll
        for (int off = 1; off < 16; off <<= 1)
#pragma unroll
            for (int j = 0; j < 4; ++j) mx[j] = fmaxf(mx[j], __shfl_xor(mx[j], off, 64));
        float al[4];
#pragma unroll
        for (int j = 0; j < 4; ++j) {
            float nm = fmaxf(m_run[j], mx[j]);
            al[j] = __expf(m_run[j] - nm);
            m_run[j] = nm;
        }
        float pm[4][4];
#pragma unroll
        for (int nt = 0; nt < 4; ++nt)
#pragma unroll
            for (int j = 0; j < 4; ++j) pm[nt][j] = __expf(s[nt][j] - m_run[j]);
        float rs[4];
#pragma unroll
        for (int j = 0; j < 4; ++j) rs[j] = pm[0][j] + pm[1][j] + pm[2][j] + pm[3][j];
#pragma unroll
        for (int off = 1; off < 16; off <<= 1)
#pragma unroll
            for (int j = 0; j < 4; ++j) rs[j] += __shfl_xor(rs[j], off, 64);
#pragma unroll
        for (int j = 0; j < 4; ++j) l_run[j] = l_run[j] * al[j] + rs[j];
#pragma unroll
        for (int ht = 0; ht < 4; ++ht)
#pragma unroll
            for (int j = 0; j < 4; ++j) oacc[ht][j] *= al[j];
#pragma unroll
        for (int nt = 0; nt < 4; ++nt)
#pragma unroll
            for (int j = 0; j < 4; ++j) Pl[w][g * 4 + j][nt * 16 + c16] = (f16)pm[nt][j];
        half8 pa0 = *reinterpret_cast<const half8*>(&Pl[w][c16][g * 8]);
        half8 pa1 = *reinterpret_cast<const half8*>(&Pl[w][c16][32 + g * 8]);
#pragma unroll
        for (int ht = 0; ht < 4; ++ht) {
            half8 vb0 = *reinterpret_cast<const half8*>(&Vt[cur][ht * 16 + c16][g * 8]);
            half8 vb1 = *reinterpret_cast<const half8*>(&Vt[cur][ht * 16 + c16][32 + g * 8]);
            oacc[ht] = mfma16(pa0, vb0, oacc[ht]);
            oacc[ht] = mfma16(pa1, vb1, oacc[ht]);
        }
        if (it + 1 < nIter) {
            *reinterpret_cast<half8*>(&Kt[cur ^ 1][sr][sc]) = kr0;
            *reinterpret_cast<half8*>(&Kt[cur ^ 1][sr][sc + 8]) = kr1;
            *reinterpret_cast<half8*>(&Vt[cur ^ 1][sr][sc]) = vr0;
            *reinterpret_cast<half8*>(&Vt[cur ^ 1][sr][sc + 8]) = vr1;
        }
        __syncthreads();
        cur ^= 1;
    }
    int slot = (((b << 6) + qt) << 2) + ck;
    f16* Op = Opart + (size_t)slot * 4096;
    float* mlp = Ml + (size_t)slot * 128;
#pragma unroll
    for (int j = 0; j < 4; ++j) {
        int r = 16 * w + g * 4 + j;
#pragma unroll
        for (int ht = 0; ht < 4; ++ht)
            Op[r * 64 + ht * 16 + c16] = (f16)oacc[ht][j];
        if (c16 == 0) { mlp[r] = m_run[j]; mlp[64 + r] = l_run[j]; }
    }
}

// ---- Kernel 4: combine split-KV partials ----
__global__ __launch_bounds__(256) void combine(const f16* __restrict__ Opart,
                                               const float* __restrict__ Ml,
                                               float* __restrict__ out) {
    int qt = blockIdx.x, b = blockIdx.y;
    int nck = (qt >> 4) + 1;
    int tid = threadIdx.x;
    int row = tid >> 2, c0 = (tid & 3) << 4;
    int bslot = ((b << 6) + qt) << 2;
    float mv[4], lv[4];
    float M = -1e30f;
#pragma unroll
    for (int i = 0; i < 4; ++i)
        if (i < nck) {
            mv[i] = Ml[(size_t)(bslot + i) * 128 + row];
            lv[i] = Ml[(size_t)(bslot + i) * 128 + 64 + row];
            M = fmaxf(M, mv[i]);
        }
    float L = 0.f, sc[4];
#pragma unroll
    for (int i = 0; i < 4; ++i)
        if (i < nck) { sc[i] = __expf(mv[i] - M); L += lv[i] * sc[i]; }
    float inv = 1.0f / L;
    float o[16];
#pragma unroll
    for (int j = 0; j < 16; ++j) o[j] = 0.f;
#pragma unroll
    for (int i = 0; i < 4; ++i)
        if (i < nck) {
            const f16* Op = Opart + (size_t)(bslot + i) * 4096 + row * 64 + c0;
            half8 h0 = *reinterpret_cast<const half8*>(Op);
            half8 h1 = *reinterpret_cast<const half8*>(Op + 8);
#pragma unroll
            for (int j = 0; j < 8; ++j) {
                o[j] += sc[i] * (float)h0[j];
                o[8 + j] += sc[i] * (float)h1[j];
            }
        }
    float* op = &out[((size_t)b * T_SEQ + (qt << 6) + row) * 64 + c0];
#pragma unroll
    for (int j = 0; j < 16; ++j) op[j] = o[j] * inv;
}

extern "C" void kernel_launch(void* const* d_in, const int* in_sizes, int n_in,
                              void* d_out, int out_size, void* d_ws, size_t ws_size,
                              hipStream_t stream) {
    (void)in_sizes; (void)n_in; (void)out_size; (void)ws_size;
    const float* x  = (const float*)d_in[0];
    const float* Wk = (const float*)d_in[1];
    const float* bk = (const float*)d_in[2];
    const float* Wq = (const float*)d_in[3];
    const float* bq = (const float*)d_in[4];
    const float* Wv = (const float*)d_in[5];
    const float* bv = (const float*)d_in[6];
    float* out = (float*)d_out;
    char* ws = (char*)d_ws;
    f16* Wfrag = (f16*)(ws);                        // 393216 B
    f16* Qb    = (f16*)(ws + 393216);               // 2 MiB
    f16* Kb    = (f16*)(ws + 393216 + 2097152);     // 2 MiB
    f16* Vbt   = (f16*)(ws + 393216 + 2 * 2097152); // 2 MiB (transposed)
    f16* Opart = (f16*)(ws + 393216 + 3 * 2097152);            // 8 MiB
    float* Ml  = (float*)(ws + 393216 + 3 * 2097152 + 8388608); // 512 KiB

    prep_w<<<12, 256, 0, stream>>>(Wq, Wk, Wv, Wfrag);
    proj<<<1024, 256, 0, stream>>>(x, Wfrag, bk, bq, bv, Qb, Kb, Vbt);
    attn<<<dim3(64, 4, 4), 256, 0, stream>>>(Qb, Kb, Vbt, Opart, Ml);
    combine<<<dim3(64, 4), 256, 0, stream>>>(Opart, Ml, out);
}

// Round 5
// 167.784 us; speedup vs baseline: 1.4811x; 1.1708x over previous
//
#include <hip/hip_runtime.h>
#include <hip/hip_bf16.h>

// MaskedAttentionHead: x[4,4096,1024] fp32 -> out fp32 [4,4096,64]
// Round 4: proj rewritten with one-shot LDS staging of the x tile (coalesced burst,
// single barrier, 32 barrier-free K-steps from LDS). attn/combine unchanged.

typedef _Float16 f16;
typedef f16 half4 __attribute__((ext_vector_type(4)));
typedef f16 half8 __attribute__((ext_vector_type(8)));
typedef float f32x4 __attribute__((ext_vector_type(4)));

#define T_SEQ 4096

__device__ __forceinline__ f32x4 mfma16(half8 a, half8 b, f32x4 c) {
    return __builtin_amdgcn_mfma_f32_16x16x32_f16(a, b, c, 0, 0, 0);
}

// ---- Kernel 1: pack W into fragment order Wfrag[nt][ks][lane][8] f16 ----
__global__ __launch_bounds__(256) void prep_w(const float* __restrict__ Wq,
                                              const float* __restrict__ Wk,
                                              const float* __restrict__ Wv,
                                              f16* __restrict__ Wfrag) {
    int nt = blockIdx.x;               // 0..11
    int mat = nt >> 2;
    const float* W = (mat == 0) ? Wq : (mat == 1 ? Wk : Wv);
    float s = (mat == 0) ? 0.125f : 1.0f;   // fold softmax scale into Wq
    int tid = threadIdx.x;
    int lane = tid & 63, g = lane >> 4, c16 = lane & 15;
    int ksb = (tid >> 6) * 8;
    int h = ((nt & 3) << 4) + c16;
#pragma unroll
    for (int q = 0; q < 8; ++q) {
        int ks = ksb + q;
        half8 o;
#pragma unroll
        for (int j = 0; j < 8; ++j) {
            int k = ks * 32 + g * 8 + j;
            o[j] = (f16)(W[(size_t)k * 64 + h] * s);
        }
        *reinterpret_cast<half8*>(&Wfrag[((size_t)(nt * 32 + ks) * 64 + lane) * 8]) = o;
    }
}

// ---- Kernel 2: QKV projection with one-shot LDS x-staging ----
// 1024 blocks x 256 thr; block = 16 rows, wave w owns n-tiles w*3..w*3+2.
// Q,K row-major [16384][64]; V transposed [4][64][4096].
__global__ __launch_bounds__(256, 4) void proj(const float* __restrict__ x,
                                               const f16* __restrict__ Wfrag,
                                               const float* __restrict__ bk,
                                               const float* __restrict__ bq,
                                               const float* __restrict__ bv,
                                               f16* __restrict__ Qb, f16* __restrict__ Kb,
                                               f16* __restrict__ Vbt) {
    __shared__ f16 xs[16][1032];   // +8 f16 pad -> 4-bank row shift, conflict-free reads
    int m0 = blockIdx.x << 4;
    int tid = threadIdx.x;
    int w = tid >> 6, lane = tid & 63, g = lane >> 4, c16 = lane & 15;

    // ---- stage x tile: 16 rows x 1024 cols, f32 -> f16, fully coalesced ----
    {
        int row = tid >> 4;            // 0..15
        int c0 = (tid & 15) << 2;      // 0..60
        const float* xr = &x[(size_t)(m0 + row) * 1024 + c0];
#pragma unroll
        for (int chunk = 0; chunk < 8; ++chunk) {
            float4 A = *reinterpret_cast<const float4*>(xr + chunk * 128);
            float4 B = *reinterpret_cast<const float4*>(xr + chunk * 128 + 64);
            half4 ha, hb;
            ha[0] = (f16)A.x; ha[1] = (f16)A.y; ha[2] = (f16)A.z; ha[3] = (f16)A.w;
            hb[0] = (f16)B.x; hb[1] = (f16)B.y; hb[2] = (f16)B.z; hb[3] = (f16)B.w;
            *reinterpret_cast<half4*>(&xs[row][c0 + chunk * 128]) = ha;
            *reinterpret_cast<half4*>(&xs[row][c0 + chunk * 128 + 64]) = hb;
        }
    }
    __syncthreads();

    // ---- 32 barrier-free K-steps from LDS ----
    f32x4 zero = {0.f, 0.f, 0.f, 0.f};
    f32x4 acc[3];
#pragma unroll
    for (int i = 0; i < 3; ++i) acc[i] = zero;
    const f16* wbase = &Wfrag[(size_t)(w * 3) * 32 * 64 * 8 + (size_t)lane * 8];
#pragma unroll 8
    for (int ks = 0; ks < 32; ++ks) {
        half8 a = *reinterpret_cast<const half8*>(&xs[c16][ks * 32 + g * 8]);
#pragma unroll
        for (int i = 0; i < 3; ++i) {
            half8 bf = *reinterpret_cast<const half8*>(
                wbase + ((size_t)i * 32 + ks) * 64 * 8);
            acc[i] = mfma16(a, bf, acc[i]);
        }
    }
    int b = m0 >> 12;
#pragma unroll
    for (int i = 0; i < 3; ++i) {
        int nt = w * 3 + i;
        int mat = nt >> 2;
        int h = ((nt & 3) << 4) + c16;
        float bias = (mat == 0) ? bq[h] * 0.125f : (mat == 1 ? bk[h] : bv[h]);
#pragma unroll
        for (int j = 0; j < 4; ++j) {
            int row = m0 + g * 4 + j;
            f16 val = (f16)(acc[i][j] + bias);
            if (mat == 0) Qb[(size_t)row * 64 + h] = val;
            else if (mat == 1) Kb[(size_t)row * 64 + h] = val;
            else Vbt[((size_t)(b * 64 + h)) * 4096 + (row & 4095)] = val;
        }
    }
}

// ---- Kernel 3: flash attention over one KV chunk (<=16 tiles of 64 keys) ----
__global__ __launch_bounds__(256) void attn(const f16* __restrict__ Qb,
                                            const f16* __restrict__ Kb,
                                            const f16* __restrict__ Vbt,
                                            f16* __restrict__ Opart,
                                            float* __restrict__ Ml) {
    int qt = blockIdx.x, b = blockIdx.y, ck = blockIdx.z;
    int t0 = ck << 4;
    if (t0 > qt) return;
    int nT = min(t0 + 16, qt + 1);
    int nIter = nT - t0;
    int q0 = qt << 6;
    const f16* Q = Qb + (size_t)b * T_SEQ * 64;
    const f16* K = Kb + (size_t)b * T_SEQ * 64;
    const f16* Vg = Vbt + (size_t)b * 64 * T_SEQ;
    int tid = threadIdx.x;
    int w = tid >> 6, lane = tid & 63, g = lane >> 4, c16 = lane & 15;
    __shared__ f16 Kt[2][64][72];   // [buf][key][h]
    __shared__ f16 Vt[2][64][72];   // [buf][h][key]
    __shared__ f16 Pl[4][16][72];

    half8 qf0 = *reinterpret_cast<const half8*>(&Q[(size_t)(q0 + 16 * w + c16) * 64 + g * 8]);
    half8 qf1 = *reinterpret_cast<const half8*>(&Q[(size_t)(q0 + 16 * w + c16) * 64 + 32 + g * 8]);

    f32x4 zero = {0.f, 0.f, 0.f, 0.f};
    f32x4 oacc[4];
#pragma unroll
    for (int i = 0; i < 4; ++i) oacc[i] = zero;
    float m_run[4], l_run[4];
#pragma unroll
    for (int j = 0; j < 4; ++j) { m_run[j] = -__builtin_inff(); l_run[j] = 0.f; }

    int sr = tid >> 2, sc = (tid & 3) << 4;
    int k0 = t0 << 6;
    half8 kr0 = *reinterpret_cast<const half8*>(&K[(size_t)(k0 + sr) * 64 + sc]);
    half8 kr1 = *reinterpret_cast<const half8*>(&K[(size_t)(k0 + sr) * 64 + sc + 8]);
    half8 vr0 = *reinterpret_cast<const half8*>(&Vg[(size_t)sr * T_SEQ + k0 + sc]);
    half8 vr1 = *reinterpret_cast<const half8*>(&Vg[(size_t)sr * T_SEQ + k0 + sc + 8]);
    *reinterpret_cast<half8*>(&Kt[0][sr][sc]) = kr0;
    *reinterpret_cast<half8*>(&Kt[0][sr][sc + 8]) = kr1;
    *reinterpret_cast<half8*>(&Vt[0][sr][sc]) = vr0;
    *reinterpret_cast<half8*>(&Vt[0][sr][sc + 8]) = vr1;
    __syncthreads();
    int cur = 0;

    for (int it = 0; it < nIter; ++it) {
        int gt = t0 + it;
        if (it + 1 < nIter) {
            int kn = (gt + 1) << 6;
            kr0 = *reinterpret_cast<const half8*>(&K[(size_t)(kn + sr) * 64 + sc]);
            kr1 = *reinterpret_cast<const half8*>(&K[(size_t)(kn + sr) * 64 + sc + 8]);
            vr0 = *reinterpret_cast<const half8*>(&Vg[(size_t)sr * T_SEQ + kn + sc]);
            vr1 = *reinterpret_cast<const half8*>(&Vg[(size_t)sr * T_SEQ + kn + sc + 8]);
        }
        f32x4 s[4];
#pragma unroll
        for (int nt = 0; nt < 4; ++nt) s[nt] = zero;
#pragma unroll
        for (int nt = 0; nt < 4; ++nt) {
            half8 b0 = *reinterpret_cast<const half8*>(&Kt[cur][nt * 16 + c16][g * 8]);
            half8 b1 = *reinterpret_cast<const half8*>(&Kt[cur][nt * 16 + c16][32 + g * 8]);
            s[nt] = mfma16(qf0, b0, s[nt]);
            s[nt] = mfma16(qf1, b1, s[nt]);
        }
        if (gt == qt) {
            int kb = gt << 6;
#pragma unroll
            for (int nt = 0; nt < 4; ++nt)
#pragma unroll
                for (int j = 0; j < 4; ++j)
                    if (kb + nt * 16 + c16 > q0 + 16 * w + g * 4 + j) s[nt][j] = -1e30f;
        }
        float mx[4];
#pragma unroll
        for (int j = 0; j < 4; ++j)
            mx[j] = fmaxf(fmaxf(s[0][j], s[1][j]), fmaxf(s[2][j], s[3][j]));
#pragma unroll
        for (int off = 1; off < 16; off <<= 1)
#pragma unroll
            for (int j = 0; j < 4; ++j) mx[j] = fmaxf(mx[j], __shfl_xor(mx[j], off, 64));
        float al[4];
#pragma unroll
        for (int j = 0; j < 4; ++j) {
            float nm = fmaxf(m_run[j], mx[j]);
            al[j] = __expf(m_run[j] - nm);
            m_run[j] = nm;
        }
        float pm[4][4];
#pragma unroll
        for (int nt = 0; nt < 4; ++nt)
#pragma unroll
            for (int j = 0; j < 4; ++j) pm[nt][j] = __expf(s[nt][j] - m_run[j]);
        float rs[4];
#pragma unroll
        for (int j = 0; j < 4; ++j) rs[j] = pm[0][j] + pm[1][j] + pm[2][j] + pm[3][j];
#pragma unroll
        for (int off = 1; off < 16; off <<= 1)
#pragma unroll
            for (int j = 0; j < 4; ++j) rs[j] += __shfl_xor(rs[j], off, 64);
#pragma unroll
        for (int j = 0; j < 4; ++j) l_run[j] = l_run[j] * al[j] + rs[j];
#pragma unroll
        for (int ht = 0; ht < 4; ++ht)
#pragma unroll
            for (int j = 0; j < 4; ++j) oacc[ht][j] *= al[j];
#pragma unroll
        for (int nt = 0; nt < 4; ++nt)
#pragma unroll
            for (int j = 0; j < 4; ++j) Pl[w][g * 4 + j][nt * 16 + c16] = (f16)pm[nt][j];
        half8 pa0 = *reinterpret_cast<const half8*>(&Pl[w][c16][g * 8]);
        half8 pa1 = *reinterpret_cast<const half8*>(&Pl[w][c16][32 + g * 8]);
#pragma unroll
        for (int ht = 0; ht < 4; ++ht) {
            half8 vb0 = *reinterpret_cast<const half8*>(&Vt[cur][ht * 16 + c16][g * 8]);
            half8 vb1 = *reinterpret_cast<const half8*>(&Vt[cur][ht * 16 + c16][32 + g * 8]);
            oacc[ht] = mfma16(pa0, vb0, oacc[ht]);
            oacc[ht] = mfma16(pa1, vb1, oacc[ht]);
        }
        if (it + 1 < nIter) {
            *reinterpret_cast<half8*>(&Kt[cur ^ 1][sr][sc]) = kr0;
            *reinterpret_cast<half8*>(&Kt[cur ^ 1][sr][sc + 8]) = kr1;
            *reinterpret_cast<half8*>(&Vt[cur ^ 1][sr][sc]) = vr0;
            *reinterpret_cast<half8*>(&Vt[cur ^ 1][sr][sc + 8]) = vr1;
        }
        __syncthreads();
        cur ^= 1;
    }
    int slot = (((b << 6) + qt) << 2) + ck;
    f16* Op = Opart + (size_t)slot * 4096;
    float* mlp = Ml + (size_t)slot * 128;
#pragma unroll
    for (int j = 0; j < 4; ++j) {
        int r = 16 * w + g * 4 + j;
#pragma unroll
        for (int ht = 0; ht < 4; ++ht)
            Op[r * 64 + ht * 16 + c16] = (f16)oacc[ht][j];
        if (c16 == 0) { mlp[r] = m_run[j]; mlp[64 + r] = l_run[j]; }
    }
}

// ---- Kernel 4: combine split-KV partials ----
__global__ __launch_bounds__(256) void combine(const f16* __restrict__ Opart,
                                               const float* __restrict__ Ml,
                                               float* __restrict__ out) {
    int qt = blockIdx.x, b = blockIdx.y;
    int nck = (qt >> 4) + 1;
    int tid = threadIdx.x;
    int row = tid >> 2, c0 = (tid & 3) << 4;
    int bslot = ((b << 6) + qt) << 2;
    float mv[4], lv[4];
    float M = -1e30f;
#pragma unroll
    for (int i = 0; i < 4; ++i)
        if (i < nck) {
            mv[i] = Ml[(size_t)(bslot + i) * 128 + row];
            lv[i] = Ml[(size_t)(bslot + i) * 128 + 64 + row];
            M = fmaxf(M, mv[i]);
        }
    float L = 0.f, sc[4];
#pragma unroll
    for (int i = 0; i < 4; ++i)
        if (i < nck) { sc[i] = __expf(mv[i] - M); L += lv[i] * sc[i]; }
    float inv = 1.0f / L;
    float o[16];
#pragma unroll
    for (int j = 0; j < 16; ++j) o[j] = 0.f;
#pragma unroll
    for (int i = 0; i < 4; ++i)
        if (i < nck) {
            const f16* Op = Opart + (size_t)(bslot + i) * 4096 + row * 64 + c0;
            half8 h0 = *reinterpret_cast<const half8*>(Op);
            half8 h1 = *reinterpret_cast<const half8*>(Op + 8);
#pragma unroll
            for (int j = 0; j < 8; ++j) {
                o[j] += sc[i] * (float)h0[j];
                o[8 + j] += sc[i] * (float)h1[j];
            }
        }
    float* op = &out[((size_t)b * T_SEQ + (qt << 6) + row) * 64 + c0];
#pragma unroll
    for (int j = 0; j < 16; ++j) op[j] = o[j] * inv;
}

extern "C" void kernel_launch(void* const* d_in, const int* in_sizes, int n_in,
                              void* d_out, int out_size, void* d_ws, size_t ws_size,
                              hipStream_t stream) {
    (void)in_sizes; (void)n_in; (void)out_size; (void)ws_size;
    const float* x  = (const float*)d_in[0];
    const float* Wk = (const float*)d_in[1];
    const float* bk = (const float*)d_in[2];
    const float* Wq = (const float*)d_in[3];
    const float* bq = (const float*)d_in[4];
    const float* Wv = (const float*)d_in[5];
    const float* bv = (const float*)d_in[6];
    float* out = (float*)d_out;
    char* ws = (char*)d_ws;
    f16* Wfrag = (f16*)(ws);                        // 393216 B
    f16* Qb    = (f16*)(ws + 393216);               // 2 MiB
    f16* Kb    = (f16*)(ws + 393216 + 2097152);     // 2 MiB
    f16* Vbt   = (f16*)(ws + 393216 + 2 * 2097152); // 2 MiB (transposed)
    f16* Opart = (f16*)(ws + 393216 + 3 * 2097152);            // 8 MiB
    float* Ml  = (float*)(ws + 393216 + 3 * 2097152 + 8388608); // 512 KiB

    prep_w<<<12, 256, 0, stream>>>(Wq, Wk, Wv, Wfrag);
    proj<<<1024, 256, 0, stream>>>(x, Wfrag, bk, bq, bv, Qb, Kb, Vbt);
    attn<<<dim3(64, 4, 4), 256, 0, stream>>>(Qb, Kb, Vbt, Opart, Ml);
    combine<<<dim3(64, 4), 256, 0, stream>>>(Opart, Ml, out);
}

// Round 6
// 159.200 us; speedup vs baseline: 1.5609x; 1.0539x over previous
//
#include <hip/hip_runtime.h>
#include <hip/hip_bf16.h>

// MaskedAttentionHead: x[4,4096,1024] fp32 -> out fp32 [4,4096,64]
// Round 5: attn rewritten with swapped-operand S^T MFMA -> in-lane softmax
// (shuffles 32->4/iter, P-writes 16 scalar -> 4x b64), exp2-domain softmax
// (log2e folded into Q scale), big-qt-first dispatch. proj/prep_w unchanged.

typedef _Float16 f16;
typedef f16 half4 __attribute__((ext_vector_type(4)));
typedef f16 half8 __attribute__((ext_vector_type(8)));
typedef float f32x4 __attribute__((ext_vector_type(4)));

#define T_SEQ 4096
// 0.125 (1/sqrt(64)) * log2(e): softmax computed in exp2 domain
#define QSCL 0.1803368801111204f

__device__ __forceinline__ f32x4 mfma16(half8 a, half8 b, f32x4 c) {
    return __builtin_amdgcn_mfma_f32_16x16x32_f16(a, b, c, 0, 0, 0);
}

// ---- Kernel 1: pack W into fragment order Wfrag[nt][ks][lane][8] f16 ----
__global__ __launch_bounds__(256) void prep_w(const float* __restrict__ Wq,
                                              const float* __restrict__ Wk,
                                              const float* __restrict__ Wv,
                                              f16* __restrict__ Wfrag) {
    int nt = blockIdx.x;               // 0..11
    int mat = nt >> 2;
    const float* W = (mat == 0) ? Wq : (mat == 1 ? Wk : Wv);
    float s = (mat == 0) ? QSCL : 1.0f;
    int tid = threadIdx.x;
    int lane = tid & 63, g = lane >> 4, c16 = lane & 15;
    int ksb = (tid >> 6) * 8;
    int h = ((nt & 3) << 4) + c16;
#pragma unroll
    for (int q = 0; q < 8; ++q) {
        int ks = ksb + q;
        half8 o;
#pragma unroll
        for (int j = 0; j < 8; ++j) {
            int k = ks * 32 + g * 8 + j;
            o[j] = (f16)(W[(size_t)k * 64 + h] * s);
        }
        *reinterpret_cast<half8*>(&Wfrag[((size_t)(nt * 32 + ks) * 64 + lane) * 8]) = o;
    }
}

// ---- Kernel 2: QKV projection with one-shot LDS x-staging (unchanged) ----
__global__ __launch_bounds__(256, 4) void proj(const float* __restrict__ x,
                                               const f16* __restrict__ Wfrag,
                                               const float* __restrict__ bk,
                                               const float* __restrict__ bq,
                                               const float* __restrict__ bv,
                                               f16* __restrict__ Qb, f16* __restrict__ Kb,
                                               f16* __restrict__ Vbt) {
    __shared__ f16 xs[16][1032];
    int m0 = blockIdx.x << 4;
    int tid = threadIdx.x;
    int w = tid >> 6, lane = tid & 63, g = lane >> 4, c16 = lane & 15;
    {
        int row = tid >> 4;
        int c0 = (tid & 15) << 2;
        const float* xr = &x[(size_t)(m0 + row) * 1024 + c0];
#pragma unroll
        for (int chunk = 0; chunk < 8; ++chunk) {
            float4 A = *reinterpret_cast<const float4*>(xr + chunk * 128);
            float4 B = *reinterpret_cast<const float4*>(xr + chunk * 128 + 64);
            half4 ha, hb;
            ha[0] = (f16)A.x; ha[1] = (f16)A.y; ha[2] = (f16)A.z; ha[3] = (f16)A.w;
            hb[0] = (f16)B.x; hb[1] = (f16)B.y; hb[2] = (f16)B.z; hb[3] = (f16)B.w;
            *reinterpret_cast<half4*>(&xs[row][c0 + chunk * 128]) = ha;
            *reinterpret_cast<half4*>(&xs[row][c0 + chunk * 128 + 64]) = hb;
        }
    }
    __syncthreads();
    f32x4 zero = {0.f, 0.f, 0.f, 0.f};
    f32x4 acc[3];
#pragma unroll
    for (int i = 0; i < 3; ++i) acc[i] = zero;
    const f16* wbase = &Wfrag[(size_t)(w * 3) * 32 * 64 * 8 + (size_t)lane * 8];
#pragma unroll 8
    for (int ks = 0; ks < 32; ++ks) {
        half8 a = *reinterpret_cast<const half8*>(&xs[c16][ks * 32 + g * 8]);
#pragma unroll
        for (int i = 0; i < 3; ++i) {
            half8 bf = *reinterpret_cast<const half8*>(
                wbase + ((size_t)i * 32 + ks) * 64 * 8);
            acc[i] = mfma16(a, bf, acc[i]);
        }
    }
    int b = m0 >> 12;
#pragma unroll
    for (int i = 0; i < 3; ++i) {
        int nt = w * 3 + i;
        int mat = nt >> 2;
        int h = ((nt & 3) << 4) + c16;
        float bias = (mat == 0) ? bq[h] * QSCL : (mat == 1 ? bk[h] : bv[h]);
#pragma unroll
        for (int j = 0; j < 4; ++j) {
            int row = m0 + g * 4 + j;
            f16 val = (f16)(acc[i][j] + bias);
            if (mat == 0) Qb[(size_t)row * 64 + h] = val;
            else if (mat == 1) Kb[(size_t)row * 64 + h] = val;
            else Vbt[((size_t)(b * 64 + h)) * 4096 + (row & 4095)] = val;
        }
    }
}

// ---- Kernel 3: flash attention, swapped-operand S^T + in-lane softmax ----
__global__ __launch_bounds__(256) void attn(const f16* __restrict__ Qb,
                                            const f16* __restrict__ Kb,
                                            const f16* __restrict__ Vbt,
                                            f16* __restrict__ Opart,
                                            float* __restrict__ Ml) {
    int qt = 63 - blockIdx.x;            // big tiles dispatched first (LPT)
    int b = blockIdx.y, ck = blockIdx.z;
    int t0 = ck << 4;
    if (t0 > qt) return;
    int nT = min(t0 + 16, qt + 1);
    int nIter = nT - t0;
    int q0 = qt << 6;
    const f16* Q = Qb + (size_t)b * T_SEQ * 64;
    const f16* K = Kb + (size_t)b * T_SEQ * 64;
    const f16* Vg = Vbt + (size_t)b * 64 * T_SEQ;
    int tid = threadIdx.x;
    int w = tid >> 6, lane = tid & 63, g = lane >> 4, c16 = lane & 15;
    __shared__ f16 Kt[2][64][72];   // [buf][key][h]
    __shared__ f16 Vt[2][64][72];   // [buf][h][key]
    __shared__ f16 Pl[4][16][72];   // [wave][qrow][key]

    // Q fragment: row q0+16w+c16, k = h (serves as B-operand of S^T mfma)
    half8 qf0 = *reinterpret_cast<const half8*>(&Q[(size_t)(q0 + 16 * w + c16) * 64 + g * 8]);
    half8 qf1 = *reinterpret_cast<const half8*>(&Q[(size_t)(q0 + 16 * w + c16) * 64 + 32 + g * 8]);

    f32x4 zero = {0.f, 0.f, 0.f, 0.f};
    f32x4 oacc[4];    // O^T: oacc[ht][jj] = O[qrow=c16][h=ht*16+g*4+jj]
#pragma unroll
    for (int i = 0; i < 4; ++i) oacc[i] = zero;
    float m_run = -__builtin_inff(), l_run = 0.f;   // per-lane qrow = c16

    int sr = tid >> 2, sc = (tid & 3) << 4;
    int k0 = t0 << 6;
    half8 kr0 = *reinterpret_cast<const half8*>(&K[(size_t)(k0 + sr) * 64 + sc]);
    half8 kr1 = *reinterpret_cast<const half8*>(&K[(size_t)(k0 + sr) * 64 + sc + 8]);
    half8 vr0 = *reinterpret_cast<const half8*>(&Vg[(size_t)sr * T_SEQ + k0 + sc]);
    half8 vr1 = *reinterpret_cast<const half8*>(&Vg[(size_t)sr * T_SEQ + k0 + sc + 8]);
    *reinterpret_cast<half8*>(&Kt[0][sr][sc]) = kr0;
    *reinterpret_cast<half8*>(&Kt[0][sr][sc + 8]) = kr1;
    *reinterpret_cast<half8*>(&Vt[0][sr][sc]) = vr0;
    *reinterpret_cast<half8*>(&Vt[0][sr][sc + 8]) = vr1;
    __syncthreads();
    int cur = 0;

    for (int it = 0; it < nIter; ++it) {
        int gt = t0 + it;
        if (it + 1 < nIter) {
            int kn = (gt + 1) << 6;
            kr0 = *reinterpret_cast<const half8*>(&K[(size_t)(kn + sr) * 64 + sc]);
            kr1 = *reinterpret_cast<const half8*>(&K[(size_t)(kn + sr) * 64 + sc + 8]);
            vr0 = *reinterpret_cast<const half8*>(&Vg[(size_t)sr * T_SEQ + kn + sc]);
            vr1 = *reinterpret_cast<const half8*>(&Vg[(size_t)sr * T_SEQ + kn + sc + 8]);
        }
        // S^T = K · Q^T : lane holds S[qrow=c16][key = nt*16+g*4+jj]
        f32x4 st[4];
#pragma unroll
        for (int nt = 0; nt < 4; ++nt) st[nt] = zero;
#pragma unroll
        for (int nt = 0; nt < 4; ++nt) {
            half8 kf0 = *reinterpret_cast<const half8*>(&Kt[cur][nt * 16 + c16][g * 8]);
            half8 kf1 = *reinterpret_cast<const half8*>(&Kt[cur][nt * 16 + c16][32 + g * 8]);
            st[nt] = mfma16(kf0, qf0, st[nt]);   // A = K frag, B = Q frag
            st[nt] = mfma16(kf1, qf1, st[nt]);
        }
        if (gt == qt) {    // causal mask on diagonal tile
            int kb = gt << 6;
            int qr = q0 + 16 * w + c16;
#pragma unroll
            for (int nt = 0; nt < 4; ++nt)
#pragma unroll
                for (int jj = 0; jj < 4; ++jj)
                    if (kb + nt * 16 + g * 4 + jj > qr) st[nt][jj] = -1e30f;
        }
        // in-lane max over 16 values, then reduce across the 4 g-lanes
        float m01, m23, mx;
        {
            f32x4 a = st[0], bq4 = st[1], c = st[2], d = st[3];
            f32x4 e;
            e[0] = fmaxf(fmaxf(a[0], a[1]), fmaxf(a[2], a[3]));
            e[1] = fmaxf(fmaxf(bq4[0], bq4[1]), fmaxf(bq4[2], bq4[3]));
            e[2] = fmaxf(fmaxf(c[0], c[1]), fmaxf(c[2], c[3]));
            e[3] = fmaxf(fmaxf(d[0], d[1]), fmaxf(d[2], d[3]));
            m01 = fmaxf(e[0], e[1]); m23 = fmaxf(e[2], e[3]);
            mx = fmaxf(m01, m23);
        }
        mx = fmaxf(mx, __shfl_xor(mx, 16, 64));
        mx = fmaxf(mx, __shfl_xor(mx, 32, 64));
        float nm = fmaxf(m_run, mx);
        float al = exp2f(m_run - nm);
        m_run = nm;
        // P = exp2(S - m), in-lane sum, cross-g reduce
        float pm[4][4];
        float rs = 0.f;
#pragma unroll
        for (int nt = 0; nt < 4; ++nt) {
            float s0 = exp2f(st[nt][0] - m_run);
            float s1 = exp2f(st[nt][1] - m_run);
            float s2 = exp2f(st[nt][2] - m_run);
            float s3 = exp2f(st[nt][3] - m_run);
            pm[nt][0] = s0; pm[nt][1] = s1; pm[nt][2] = s2; pm[nt][3] = s3;
            rs += (s0 + s1) + (s2 + s3);
        }
        rs += __shfl_xor(rs, 16, 64);
        rs += __shfl_xor(rs, 32, 64);
        l_run = l_run * al + rs;
#pragma unroll
        for (int ht = 0; ht < 4; ++ht)
#pragma unroll
            for (int jj = 0; jj < 4; ++jj) oacc[ht][jj] *= al;
        // P^T pack: lane's keys nt*16+g*4..+3 are contiguous -> 4x b64 writes
#pragma unroll
        for (int nt = 0; nt < 4; ++nt) {
            half4 p4;
            p4[0] = (f16)pm[nt][0]; p4[1] = (f16)pm[nt][1];
            p4[2] = (f16)pm[nt][2]; p4[3] = (f16)pm[nt][3];
            *reinterpret_cast<half4*>(&Pl[w][c16][nt * 16 + g * 4]) = p4;
        }
        // PV: O^T = V^T · P^T  (A = V^T frag from Vt, B = P^T frag from Pl)
        half8 pa0 = *reinterpret_cast<const half8*>(&Pl[w][c16][g * 8]);
        half8 pa1 = *reinterpret_cast<const half8*>(&Pl[w][c16][32 + g * 8]);
#pragma unroll
        for (int ht = 0; ht < 4; ++ht) {
            half8 vb0 = *reinterpret_cast<const half8*>(&Vt[cur][ht * 16 + c16][g * 8]);
            half8 vb1 = *reinterpret_cast<const half8*>(&Vt[cur][ht * 16 + c16][32 + g * 8]);
            oacc[ht] = mfma16(vb0, pa0, oacc[ht]);
            oacc[ht] = mfma16(vb1, pa1, oacc[ht]);
        }
        if (it + 1 < nIter) {
            *reinterpret_cast<half8*>(&Kt[cur ^ 1][sr][sc]) = kr0;
            *reinterpret_cast<half8*>(&Kt[cur ^ 1][sr][sc + 8]) = kr1;
            *reinterpret_cast<half8*>(&Vt[cur ^ 1][sr][sc]) = vr0;
            *reinterpret_cast<half8*>(&Vt[cur ^ 1][sr][sc + 8]) = vr1;
        }
        __syncthreads();
        cur ^= 1;
    }
    // epilogue: partial O (f16, lane's qrow = c16, h = ht*16+g*4+jj) + m/l
    int slot = (((b << 6) + qt) << 2) + ck;
    f16* Op = Opart + (size_t)slot * 4096;
    float* mlp = Ml + (size_t)slot * 128;
    int r = 16 * w + c16;
#pragma unroll
    for (int ht = 0; ht < 4; ++ht) {
        half4 o4;
        o4[0] = (f16)oacc[ht][0]; o4[1] = (f16)oacc[ht][1];
        o4[2] = (f16)oacc[ht][2]; o4[3] = (f16)oacc[ht][3];
        *reinterpret_cast<half4*>(&Op[r * 64 + ht * 16 + g * 4]) = o4;
    }
    if (g == 0) { mlp[r] = m_run; mlp[64 + r] = l_run; }
}

// ---- Kernel 4: combine split-KV partials (exp2 domain) ----
__global__ __launch_bounds__(256) void combine(const f16* __restrict__ Opart,
                                               const float* __restrict__ Ml,
                                               float* __restrict__ out) {
    int qt = blockIdx.x, b = blockIdx.y;
    int nck = (qt >> 4) + 1;
    int tid = threadIdx.x;
    int row = tid >> 2, c0 = (tid & 3) << 4;
    int bslot = ((b << 6) + qt) << 2;
    float mv[4], lv[4];
    float M = -1e30f;
#pragma unroll
    for (int i = 0; i < 4; ++i)
        if (i < nck) {
            mv[i] = Ml[(size_t)(bslot + i) * 128 + row];
            lv[i] = Ml[(size_t)(bslot + i) * 128 + 64 + row];
            M = fmaxf(M, mv[i]);
        }
    float L = 0.f, sc[4];
#pragma unroll
    for (int i = 0; i < 4; ++i)
        if (i < nck) { sc[i] = exp2f(mv[i] - M); L += lv[i] * sc[i]; }
    float inv = 1.0f / L;
    float o[16];
#pragma unroll
    for (int j = 0; j < 16; ++j) o[j] = 0.f;
#pragma unroll
    for (int i = 0; i < 4; ++i)
        if (i < nck) {
            const f16* Op = Opart + (size_t)(bslot + i) * 4096 + row * 64 + c0;
            half8 h0 = *reinterpret_cast<const half8*>(Op);
            half8 h1 = *reinterpret_cast<const half8*>(Op + 8);
#pragma unroll
            for (int j = 0; j < 8; ++j) {
                o[j] += sc[i] * (float)h0[j];
                o[8 + j] += sc[i] * (float)h1[j];
            }
        }
    float* op = &out[((size_t)b * T_SEQ + (qt << 6) + row) * 64 + c0];
#pragma unroll
    for (int j = 0; j < 16; ++j) op[j] = o[j] * inv;
}

extern "C" void kernel_launch(void* const* d_in, const int* in_sizes, int n_in,
                              void* d_out, int out_size, void* d_ws, size_t ws_size,
                              hipStream_t stream) {
    (void)in_sizes; (void)n_in; (void)out_size; (void)ws_size;
    const float* x  = (const float*)d_in[0];
    const float* Wk = (const float*)d_in[1];
    const float* bk = (const float*)d_in[2];
    const float* Wq = (const float*)d_in[3];
    const float* bq = (const float*)d_in[4];
    const float* Wv = (const float*)d_in[5];
    const float* bv = (const float*)d_in[6];
    float* out = (float*)d_out;
    char* ws = (char*)d_ws;
    f16* Wfrag = (f16*)(ws);                        // 393216 B
    f16* Qb    = (f16*)(ws + 393216);               // 2 MiB
    f16* Kb    = (f16*)(ws + 393216 + 2097152);     // 2 MiB
    f16* Vbt   = (f16*)(ws + 393216 + 2 * 2097152); // 2 MiB (transposed)
    f16* Opart = (f16*)(ws + 393216 + 3 * 2097152);            // 8 MiB
    float* Ml  = (float*)(ws + 393216 + 3 * 2097152 + 8388608); // 512 KiB

    prep_w<<<12, 256, 0, stream>>>(Wq, Wk, Wv, Wfrag);
    proj<<<1024, 256, 0, stream>>>(x, Wfrag, bk, bq, bv, Qb, Kb, Vbt);
    attn<<<dim3(64, 4, 4), 256, 0, stream>>>(Qb, Kb, Vbt, Opart, Ml);
    combine<<<dim3(64, 4), 256, 0, stream>>>(Opart, Ml, out);
}